// Round 9
// baseline (188.769 us; speedup 1.0000x reference)
//
#include <hip/hip_runtime.h>
#include <hip/hip_bf16.h>
#include <stdint.h>

// ---------------------------------------------------------------------------
// CrossAttention B=4 N=512 M=2048 C=1024 H=16 D=64, bf16 MFMA fp32 accum.
// R18b: identical to R18 (broker capacity timeout; resubmitting unchanged).
// R18: unify gemm_qkv on the proven 128x128 single-GEMM shape + R17 dbuf.
// R16's 128x64 dual-output KV tile halved per-wave MFMA density (32 MFMA vs
// 6 ds_read+8 llds16 per k-step); with R17's double-buffer providing
// latency-hiding inside the block, density beats occupancy. K-proj and
// V-proj are now separate 128x128 blocks (64 MFMA/wave/step, m97 shape),
// all three projections share one dbuf gemm_body + R13's mode-0/2 epilogue
// (hardware-verified layouts). Grid: K [0,L*8), V [L*8,2L*8), Q tail.
// A-panels staged twice (K,V) -- extra L2-resident reads hidden under MFMA.
// Numerics bit-identical (same per-element MFMA order; absmax 0.0004882812).
// Carried from R17: 2-phase dbuf k-loop (one barrier/step) in gemm_qkv and
// gemm_o, bf16 scatter-cast cb, mask_meta scan, frag-major Q/K/V,
// fixed-max softmax attn.
// ---------------------------------------------------------------------------

typedef __attribute__((ext_vector_type(4))) float f32x4;
typedef __attribute__((ext_vector_type(8))) __bf16 bf16x8;
typedef __attribute__((ext_vector_type(8))) unsigned short u16x8;

#define DEVI __device__ __forceinline__

// SCALE * log2(e): folded into Wq cast so QK^T scores land in log2 units.
#define QSC (0.125f * 1.44269504088896f)

DEVI f32x4 mfma16(u16x8 a, u16x8 b, f32x4 c) {
  return __builtin_amdgcn_mfma_f32_16x16x32_bf16(
      __builtin_bit_cast(bf16x8, a), __builtin_bit_cast(bf16x8, b), c, 0, 0, 0);
}

// round-to-nearest-even fp32 -> bf16
DEVI unsigned short f2bf(float f) {
  union { float f; unsigned int u; } x; x.f = f;
  unsigned int u = x.u;
  return (unsigned short)((u + 0x7fffu + ((u >> 16) & 1u)) >> 16);
}

DEVI float exp2_fast(float x) {
#if __has_builtin(__builtin_amdgcn_exp2f)
  return __builtin_amdgcn_exp2f(x);
#else
  return exp2f(x);
#endif
}

// async global->LDS, 16 bytes per lane (global_load_lds_dwordx4)
DEVI void llds16(const void* g, void* l) {
  __builtin_amdgcn_global_load_lds(
      (const __attribute__((address_space(1))) void*)g,
      (__attribute__((address_space(3))) void*)l, 16, 0, 0);
}

// ---------------------------------------------------------------------------
// Per-batch mask scan: meta[r] = scatter dst for ctx row r (bit31 = valid),
// cnt[b] = number of valid keys. One block per batch.
__global__ __launch_bounds__(256)
void mask_meta(const int* __restrict__ mask, int* __restrict__ meta,
               int* __restrict__ cnt) {
  const int b = blockIdx.x;
  const int tid = threadIdx.x;
  const int* mb = mask + b * 2048;
  int v[8], s = 0;
#pragma unroll
  for (int j = 0; j < 8; ++j) { v[j] = (mb[tid * 8 + j] != 0) ? 1 : 0; s += v[j]; }
  __shared__ int sc[2][256];
  sc[0][tid] = s;
  __syncthreads();
  int src = 0;
  for (int off = 1; off < 256; off <<= 1) {
    int x = sc[src][tid];
    if (tid >= off) x += sc[src][tid - off];
    sc[src ^ 1][tid] = x;
    src ^= 1;
    __syncthreads();
  }
  const int incl = sc[src][tid];   // inclusive over threads 0..tid
  const int c = sc[src][255];
  int pre = incl - s;              // valid rows among elements < tid*8
#pragma unroll
  for (int j = 0; j < 8; ++j) {
    const int p = tid * 8 + j;
    const unsigned dst = v[j] ? (unsigned)pre : (unsigned)(c + (p - pre));
    meta[b * 2048 + p] = (int)(dst | (v[j] ? 0x80000000u : 0u));
    pre += v[j];
  }
  if (tid == 0) cnt[b] = c;
}

// ---------------------------------------------------------------------------
// Casts all fp32 inputs to bf16. Wq gets QSC folded in. ctx rows are
// SCATTERED into compacted order using the precomputed meta[] ranks.
// Grid 3584: [0,512) x; [512,2560) ctx (4 rows/block); [2560,3584) weights.
__global__ __launch_bounds__(256)
void cast_fused(const float* __restrict__ x, const float* __restrict__ ctx,
                const float* __restrict__ wq, const float* __restrict__ wk,
                const float* __restrict__ wv, const float* __restrict__ wo,
                const int* __restrict__ meta, const int* __restrict__ cnt,
                unsigned short* __restrict__ xb, unsigned short* __restrict__ cb,
                unsigned short* __restrict__ wqb, unsigned short* __restrict__ wkb,
                unsigned short* __restrict__ wvb, unsigned short* __restrict__ wob) {
  int bid = blockIdx.x;
  const int tid = threadIdx.x;
  if (bid >= 512 && bid < 2560) {  // ctx scatter, 4 rows per block
    const int r0 = (bid - 512) * 4;
#pragma unroll
    for (int rr = 0; rr < 4; ++rr) {
      const int r = r0 + rr;
      const int b = r >> 11;
      const unsigned mv = (unsigned)meta[r];
      const int valid = (int)(mv >> 31);
      const int dst = (int)(mv & 0x7fffffffu);
      if (!valid && dst >= ((cnt[b] + 255) & ~255)) continue;  // beyond pad
      unsigned short* dp = cb + ((size_t)(b * 2048 + dst)) * 1024 + tid * 4;
      if (valid) {
        const float4 v = *(const float4*)(ctx + ((size_t)r) * 1024 + tid * 4);
        ushort4 o;
        o.x = f2bf(v.x); o.y = f2bf(v.y); o.z = f2bf(v.z); o.w = f2bf(v.w);
        *(ushort4*)dp = o;
      } else {
        ushort4 z; z.x = z.y = z.z = z.w = 0;
        *(ushort4*)dp = z;
      }
    }
    return;
  }
  const float* src; unsigned short* dst; float scale = 1.f;
  if (bid < 512) { src = x; dst = xb; }
  else {
    bid -= 2560;
    const int w = bid >> 8; bid &= 255;
    src = (w == 0) ? wq : (w == 1) ? wk : (w == 2) ? wv : wo;
    dst = (w == 0) ? wqb : (w == 1) ? wkb : (w == 2) ? wvb : wob;
    if (w == 0) scale = QSC;
  }
  const int e0 = bid * 4096 + tid * 4;
#pragma unroll
  for (int it = 0; it < 4; ++it) {
    const int e = e0 + it * 1024;
    const float4 v = *(const float4*)(src + e);
    ushort4 o;
    o.x = f2bf(v.x * scale); o.y = f2bf(v.y * scale);
    o.z = f2bf(v.z * scale); o.w = f2bf(v.w * scale);
    *(ushort4*)(dst + e) = o;
  }
}

// ---------------------------------------------------------------------------
// Epilogue helper: stage a 128x128 bf16 C tile through LDS, store coalesced.
// mode 0: fragment-major [bh][grp=idx/16][d8][idx&15][8] (bh-extent S=1<<logS).
// mode 2: V^T fragment-major [bh][key/64][d/16][key8][d&15][8].
// (R13's hardware-verified version.)
DEVI void epi_store(f32x4 (&acc)[4][4], const float* __restrict__ bias,
                    float bscale, void* __restrict__ Cout,
                    int bm, int bn, int logS, int mode,
                    unsigned short* cst, int tid, int wave, int l15, int quad) {
  const int wm = wave & 1, wn = wave >> 1;
  __syncthreads();
  for (int half = 0; half < 2; ++half) {
    if (wm == half) {
#pragma unroll
      for (int mi = 0; mi < 4; ++mi)
#pragma unroll
        for (int ni = 0; ni < 4; ++ni)
#pragma unroll
          for (int r = 0; r < 4; ++r) {
            int lrow = mi * 16 + quad * 4 + r;          // 0..63
            int lcol = wn * 64 + ni * 16 + l15;         // 0..127
            unsigned short bv = f2bf(acc[mi][ni][r] + bias[bn + lcol] * bscale);
            if (mode == 0) cst[lrow * 136 + lcol] = bv;
            else           cst[lcol * 72 + lrow] = bv;  // transposed
          }
    }
    __syncthreads();
    if (mode == 0) {
      // fragment-major: one u16x8 = (idx fixed, 8 consecutive d)
      int lrow = tid >> 2, cc = (tid & 3) * 32;
      int row = bm + half * 64 + lrow;
      int S = 1 << logS;
      int b = row >> logS, sl = row & (S - 1);
#pragma unroll
      for (int j = 0; j < 4; ++j) {
        int col = bn + cc + j * 8;
        int h = col >> 6, d8 = (col & 63) >> 3;
        size_t base = (((size_t)(b * 16 + h)) << logS) * 64 +
                      (size_t)(sl >> 4) * 1024 + d8 * 128 + (sl & 15) * 8;
        *(u16x8*)&((unsigned short*)Cout)[base] =
            *(const u16x8*)&cst[lrow * 136 + cc + j * 8];
      }
    } else {
      // V^T fragment-major: one u16x8 = (d fixed, 8 consecutive keys)
      int c = tid >> 1, rc = (tid & 1) * 32;
      int gc = bn + c, h = gc >> 6, d = gc & 63;
      int b = bm >> 11;
#pragma unroll
      for (int j = 0; j < 4; ++j) {
        int key = (bm & 2047) + half * 64 + rc + j * 8;
        size_t base = (size_t)(b * 16 + h) * 131072 +
                      (size_t)(((key >> 6) * 4 + (d >> 4)) * 8 + ((key >> 3) & 7)) * 128 +
                      (d & 15) * 8;
        *(u16x8*)&((unsigned short*)Cout)[base] =
            *(const u16x8*)&cst[c * 72 + rc + j * 8];
      }
    }
    __syncthreads();
  }
}

// ---------------------------------------------------------------------------
// Unified 128x128 single-GEMM body, DOUBLE-BUFFERED k-loop, one barrier per
// k-step (R17 schedule): stage(k+1) issues fire-and-forget llds16 into the
// other buffer, MFMA consumes the current buffer, then ONE __syncthreads()
// (compiler's vmcnt(0) drains in-flight loads AFTER compute covered their
// latency). Per-phase: As 16KB + Bs 16KB = 32 KB; dbuf = 64 KB.
DEVI void gemm_body(const unsigned short* __restrict__ A,
                    const unsigned short* __restrict__ W,
                    const float* __restrict__ bias, float bscale,
                    unsigned short* __restrict__ Cout,
                    int bm, int bn, int logS, int mode,
                    unsigned short* sh) {
  constexpr int K = 1024;
  const int tid = threadIdx.x;
  const int wave = tid >> 6, lane = tid & 63;
  const int l15 = lane & 15, quad = lane >> 4;
  const int wm = wave & 1, wn = wave >> 1;

  auto stage = [&](int p, int k0) {
    unsigned short* As = sh + p * 16384;
    unsigned short* Bs = As + 8192;
#pragma unroll
    for (int c = 0; c < 4; ++c) {
      int s = c * 256 + tid;
      int m = s >> 3, k8 = (s & 7) ^ (m & 7);
      llds16(A + (size_t)(bm + m) * K + k0 + k8 * 8, &As[s * 8]);
      llds16(W + (size_t)(bn + m) * K + k0 + k8 * 8, &Bs[s * 8]);
    }
  };

  f32x4 acc[4][4] = {};

  stage(0, 0);
  __syncthreads();

  int cur = 0;
  for (int k0 = 0; k0 < K; k0 += 64) {
    if (k0 + 64 < K) stage(cur ^ 1, k0 + 64);  // flies over the MFMA phase
    const unsigned short* As = sh + cur * 16384;
    const unsigned short* Bs = As + 8192;
#pragma unroll
    for (int ks = 0; ks < 2; ++ks) {
      const int k8 = ks * 4 + quad;
      u16x8 af[4], bf[4];
#pragma unroll
      for (int i = 0; i < 4; ++i) {
        int m = wm * 64 + i * 16 + l15;
        af[i] = *(const u16x8*)(&As[(m * 8 + (k8 ^ (m & 7))) * 8]);
        int n = wn * 64 + i * 16 + l15;
        bf[i] = *(const u16x8*)(&Bs[(n * 8 + (k8 ^ (n & 7))) * 8]);
      }
#pragma unroll
      for (int mi = 0; mi < 4; ++mi)
#pragma unroll
        for (int ni = 0; ni < 4; ++ni)
          acc[mi][ni] = mfma16(af[mi], bf[ni], acc[mi][ni]);
    }
    __syncthreads();  // drains next-tile loads (post-compute) + LDS reads
    cur ^= 1;
  }

  epi_store(acc, bias, bscale, Cout, bm, bn, logS, mode, sh, tid, wave, l15, quad);
}

// Fused Q/K/V projection, DENSE remap, all-128x128 tiles (m97 shape + dbuf).
// Flat grid 1152 blocks (max: 2*64*8+128 when cnt=2048 everywhere).
// ids [0, L*8)           : K-proj tiles (128 rows x 128 of Wk)
// ids [L*8, 2*L*8)       : V-proj tiles (same rows x Wv, V^T epilogue)
// ids [2*L*8, 2*L*8+128) : Q tiles
// ids >= 2*L*8+128       : exit immediately
__global__ __launch_bounds__(256, 2)
void gemm_qkv(const unsigned short* __restrict__ xb,
              const unsigned short* __restrict__ cb,
              const unsigned short* __restrict__ wq,
              const unsigned short* __restrict__ wk,
              const unsigned short* __restrict__ wv,
              const float* __restrict__ bq, const float* __restrict__ bk,
              const float* __restrict__ bv,
              const int* __restrict__ cnt,
              unsigned short* __restrict__ qh, unsigned short* __restrict__ kh,
              unsigned short* __restrict__ vt) {
  __shared__ __align__(16) unsigned short sh[32768];  // 64 KB, 2 phases
  const int id = blockIdx.x;

  const int nb0 = ((cnt[0] + 255) & ~255) >> 7;
  const int nb1 = ((cnt[1] + 255) & ~255) >> 7;
  const int nb2 = ((cnt[2] + 255) & ~255) >> 7;
  const int nb3 = ((cnt[3] + 255) & ~255) >> 7;
  const int L = nb0 + nb1 + nb2 + nb3;
  if (id < 2 * L * 8) {
    const int isV = (id >= L * 8);
    const int id2 = isV ? id - L * 8 : id;
    int xl = id2 >> 3, y = id2 & 7, b = 0;
    if (xl >= nb0) { xl -= nb0; b = 1;
      if (xl >= nb1) { xl -= nb1; b = 2;
        if (xl >= nb2) { xl -= nb2; b = 3; } } }
    const int bm = b * 2048 + xl * 128, bn = y * 128;
    if (isV) gemm_body(cb, wv, bv, 1.f, vt, bm, bn, 11, 2, sh);
    else     gemm_body(cb, wk, bk, 1.f, kh, bm, bn, 11, 0, sh);
  } else if (id < 2 * L * 8 + 128) {
    const int q = id - 2 * L * 8;
    gemm_body(xb, wq, bq, QSC, qh, (q & 15) * 128, (q >> 4) * 128, 9, 0, sh);
  }
}

// ---------------------------------------------------------------------------
// Output projection: out[2048,1024] fp32 = ah @ Wo^T + bo. 64x128 tile,
// grid (32, 8) = 256 blocks, double-buffered single-barrier k-loop.
// Per-phase buffer: As 8KB + Bs 16KB = 24 KB; 48 KB total.
// The ONLY kernel that touches d_out.
__global__ __launch_bounds__(256)
void gemm_o(const unsigned short* __restrict__ A,
            const unsigned short* __restrict__ W,
            const float* __restrict__ bo, float* __restrict__ out) {
  constexpr int K = 1024;
  __shared__ __align__(16) unsigned short sh[24576];  // 48 KB, 2 phases

  const int tid = threadIdx.x;
  const int wave = tid >> 6, lane = tid & 63;
  const int l15 = lane & 15, quad = lane >> 4;
  const int bm = blockIdx.x * 64, bn = blockIdx.y * 128;

  auto stage = [&](int p, int k0) {
    unsigned short* As = sh + p * 12288;
    unsigned short* Bs = As + 4096;
#pragma unroll
    for (int c = 0; c < 2; ++c) {
      int s = c * 256 + tid;
      int m = s >> 3, k8 = (s & 7) ^ (m & 7);
      llds16(A + (size_t)(bm + m) * K + k0 + k8 * 8, &As[s * 8]);
    }
#pragma unroll
    for (int c = 0; c < 4; ++c) {
      int s = c * 256 + tid;
      int m = s >> 3, k8 = (s & 7) ^ (m & 7);
      llds16(W + (size_t)(bn + m) * K + k0 + k8 * 8, &Bs[s * 8]);
    }
  };

  f32x4 acc[4][2] = {};

  stage(0, 0);
  __syncthreads();

  int cur = 0;
  for (int k0 = 0; k0 < K; k0 += 64) {
    if (k0 + 64 < K) stage(cur ^ 1, k0 + 64);
    const unsigned short* As = sh + cur * 12288;
    const unsigned short* Bs = As + 4096;
#pragma unroll
    for (int ks = 0; ks < 2; ++ks) {
      const int k8 = ks * 4 + quad;
      u16x8 af[4], bf[2];
#pragma unroll
      for (int i = 0; i < 4; ++i) {
        int m = i * 16 + l15;
        af[i] = *(const u16x8*)(&As[(m * 8 + (k8 ^ (m & 7))) * 8]);
      }
#pragma unroll
      for (int i = 0; i < 2; ++i) {
        int n = wave * 32 + i * 16 + l15;
        bf[i] = *(const u16x8*)(&Bs[(n * 8 + (k8 ^ (n & 7))) * 8]);
      }
#pragma unroll
      for (int mi = 0; mi < 4; ++mi)
#pragma unroll
        for (int ni = 0; ni < 2; ++ni)
          acc[mi][ni] = mfma16(af[mi], bf[ni], acc[mi][ni]);
    }
    __syncthreads();
    cur ^= 1;
  }

#pragma unroll
  for (int mi = 0; mi < 4; ++mi)
#pragma unroll
    for (int ni = 0; ni < 2; ++ni)
#pragma unroll
      for (int r = 0; r < 4; ++r) {
        int row = bm + mi * 16 + quad * 4 + r;
        int col = bn + wave * 32 + ni * 16 + l15;
        out[(size_t)row * 1024 + col] = acc[mi][ni][r] + bo[col];
      }
}

// ---------------------------------------------------------------------------
// Split-K flash attention over COMPACTED keys, fixed-max softmax.
// Grid (64 bh, 8 qblk), block 256. cnt from the precomputed scan (1 uniform
// load). Wave w covers keys {w*64 + 256t}, t < T = ceil(cnt/256). Bias
// register-computed: uniform -8 for full tiles, per-element (-8 / -1e30)
// when the stripe straddles cnt (pad K/V rows come from zero-filled ctx
// rows -> finite). No barriers in the main loop. Q/K/V FRAGMENT-MAJOR
// (contiguous 1KB wave-loads).
// launch_bounds(256,2): VGPR cap 256 (audit ~210) -> 2 blocks/CU resident.
// PS: p_lds row stride in u16. MUST be == 0 mod 8 (16 B) -- P fragments are
// read as u16x8 (ds_read_b128); any other stride misaligns odd q-rows.
#define PS 72
__global__ __launch_bounds__(256, 2)
void attn_kernel(const unsigned short* __restrict__ Q,   // frag-major [64][32][8][16][8]
                 const unsigned short* __restrict__ K,   // frag-major [64][128][8][16][8]
                 const unsigned short* __restrict__ Vt,  // frag-major [64][32][4][8][16][8]
                 const int* __restrict__ cnt,            // [4]
                 unsigned short* __restrict__ O) {       // [4][512][1024]
  __shared__ __align__(16) unsigned short p_lds[4][2][16 * PS];
  __shared__ float l_lds[4][64];
  __shared__ __align__(16) float o_comb[64][68];

  const int tid = threadIdx.x;
  const int wave = tid >> 6, lane = tid & 63;
  const int l15 = lane & 15, quad = lane >> 4;
  const int bh = blockIdx.x, b = bh >> 4, h = bh & 15;
  const int q0 = blockIdx.y * 64;

  const int c = cnt[b];
  const int T = (c + 255) >> 8;  // number of 256-key macro tiles

  const unsigned short* Qb = Q + (size_t)bh * 32768 + (size_t)(q0 >> 4) * 1024;
  const unsigned short* Kb = K + (size_t)bh * 131072;
  const unsigned short* Vb = Vt + (size_t)bh * 131072;

  // Q fragments (frag-major): one contiguous 1KB wave-load each.
  u16x8 aq[4][2];
#pragma unroll
  for (int qg = 0; qg < 4; ++qg)
#pragma unroll
    for (int ks = 0; ks < 2; ++ks)
      aq[qg][ks] = *(const u16x8*)(Qb + ((qg * 8 + ks * 4 + quad) * 16 + l15) * 8);

  f32x4 o_acc[4][4] = {};
  float l_s[4] = {0.f, 0.f, 0.f, 0.f};

  u16x8 kf[2][4];

  auto load_k = [&](int kb) {
    const int kg0 = kb >> 4;
#pragma unroll
    for (int ns = 0; ns < 4; ++ns)
#pragma unroll
      for (int ks = 0; ks < 2; ++ks)
        kf[ks][ns] = *(const u16x8*)(Kb + (((size_t)(kg0 + ns) * 8 + ks * 4 + quad) * 16 + l15) * 8);
  };

  load_k(wave * 64);

#pragma unroll 1
  for (int t = 0; t < T; ++t) {
    const int kb = wave * 64 + t * 256;
    const int kb_next = kb + (t + 1 < T ? 256 : 0);

    // V^T frags (frag-major, contiguous): consumed in PV, well after issue.
    u16x8 vf[2][4];
    const int kt4 = (kb >> 6) * 4;
#pragma unroll
    for (int nd = 0; nd < 4; ++nd)
#pragma unroll
      for (int ks = 0; ks < 2; ++ks)
        vf[ks][nd] = *(const u16x8*)(Vb + (((size_t)(kt4 + nd) * 8 + ks * 4 + quad) * 16 + l15) * 8);

    // register bias: uniform -8 unless this 64-key stripe straddles cnt
    f32x4 bfr[4];
    if (kb + 64 <= c) {
#pragma unroll
      for (int ns = 0; ns < 4; ++ns)
        bfr[ns] = f32x4{-8.f, -8.f, -8.f, -8.f};
    } else {
#pragma unroll
      for (int ns = 0; ns < 4; ++ns)
#pragma unroll
        for (int r = 0; r < 4; ++r)
          bfr[ns][r] = (kb + ns * 16 + quad * 4 + r < c) ? -8.f : -1e30f;
    }

#pragma unroll
    for (int qg = 0; qg < 4; ++qg) {
      // S^T tile: D[key = ns*16+quad*4+r][q = l15], C-init = bias (-8 shift)
      f32x4 sfr[4];
#pragma unroll
      for (int ns = 0; ns < 4; ++ns) {
        f32x4 sa = bfr[ns];
#pragma unroll
        for (int ks = 0; ks < 2; ++ks)
          sa = mfma16(kf[ks][ns], aq[qg][ks], sa);
        sfr[ns] = sa;
      }

      // kf dead after qg==3's S: reload for next tile now (covered by the
      // remaining softmax + PV of this qg).
      if (qg == 3) load_k(kb_next);

      float rsum = 0.f;
#pragma unroll
      for (int ns = 0; ns < 4; ++ns) {
        unsigned int pr[4];
#pragma unroll
        for (int r = 0; r < 4; ++r) {
          float p = exp2_fast(sfr[ns][r]);
          unsigned int u = __builtin_bit_cast(unsigned int, p) & 0xffff0000u;
          rsum += __builtin_bit_cast(float, u);  // sum TRUNCATED p: consistent with PV
          pr[r] = u;
        }
        uint2 pw;
        pw.x = __builtin_amdgcn_perm(pr[1], pr[0], 0x07060302u);
        pw.y = __builtin_amdgcn_perm(pr[3], pr[2], 0x07060302u);
        *(uint2*)&p_lds[wave][qg & 1][l15 * PS + ns * 16 + quad * 4] = pw;
      }
      rsum += __shfl_xor(rsum, 16, 64);
      rsum += __shfl_xor(rsum, 32, 64);
      l_s[qg] += rsum;

      // PV: A = P (lane=q, elems=key) from p_lds; B = V^T frags
#pragma unroll
      for (int ks = 0; ks < 2; ++ks) {
        u16x8 pf = *(const u16x8*)&p_lds[wave][qg & 1][l15 * PS + ks * 32 + quad * 8];
#pragma unroll
        for (int nd = 0; nd < 4; ++nd)
          o_acc[qg][nd] = mfma16(pf, vf[ks][nd], o_acc[qg][nd]);
      }
    }
  }

  // ---- combine the 4 waves' partial (l, o): plain sums (fixed max) ----
  if (quad == 0) {
#pragma unroll
    for (int qg = 0; qg < 4; ++qg)
      l_lds[wave][qg * 16 + l15] = l_s[qg];
  }
  __syncthreads();

  for (int w = 0; w < 4; ++w) {
    if (wave == w) {
#pragma unroll
      for (int qg = 0; qg < 4; ++qg)
#pragma unroll
        for (int r = 0; r < 4; ++r) {
          const int q = qg * 16 + quad * 4 + r;
#pragma unroll
          for (int nd = 0; nd < 4; ++nd) {
            const int d = nd * 16 + l15;
            float v = o_acc[qg][nd][r];
            if (w == 0) o_comb[q][d] = v;
            else        o_comb[q][d] += v;
          }
        }
    }
    __syncthreads();
  }

  // ---- final normalize + store (two u16x8 per thread) ----
  {
    const int q = tid >> 2, dc = (tid & 3) * 16;
    const float inv = 1.f / (l_lds[0][q] + l_lds[1][q] + l_lds[2][q] + l_lds[3][q]);
    unsigned short* Ob = O + ((size_t)(b * 512 + q0 + q)) * 1024 + h * 64 + dc;
    u16x8 o1, o2;
#pragma unroll
    for (int j = 0; j < 8; ++j) o1[j] = f2bf(o_comb[q][dc + j] * inv);
#pragma unroll
    for (int j = 0; j < 8; ++j) o2[j] = f2bf(o_comb[q][dc + 8 + j] * inv);
    *(u16x8*)(Ob) = o1;
    *(u16x8*)(Ob + 8) = o2;
  }
}

// ---------------------------------------------------------------------------
extern "C" void kernel_launch(void* const* d_in, const int* in_sizes, int n_in,
                              void* d_out, int out_size, void* d_ws, size_t ws_size,
                              hipStream_t stream) {
  const float* x   = (const float*)d_in[0];
  const float* ctx = (const float*)d_in[1];
  const int* mask  = (const int*)d_in[2];
  const float* Wq  = (const float*)d_in[3];
  const float* bq  = (const float*)d_in[4];
  const float* Wk  = (const float*)d_in[5];
  const float* bk  = (const float*)d_in[6];
  const float* Wv  = (const float*)d_in[7];
  const float* bv  = (const float*)d_in[8];
  const float* Wo  = (const float*)d_in[9];
  const float* bo  = (const float*)d_in[10];

  char* ws = (char*)d_ws;
  // [MB] xb 0-4, cb 4-20, w 20-28, qh 28-32, kh 32-48, vt 48-64, ah 64-68,
  // meta/cnt at 68 (8192+4 ints). All ws contents are produced fresh every
  // launch; d_out is written ONLY by gemm_o.
  unsigned short* xb  = (unsigned short*)(ws + ((size_t)0  << 20));
  unsigned short* cb  = (unsigned short*)(ws + ((size_t)4  << 20));
  unsigned short* wqb = (unsigned short*)(ws + ((size_t)20 << 20));
  unsigned short* wkb = (unsigned short*)(ws + ((size_t)22 << 20));
  unsigned short* wvb = (unsigned short*)(ws + ((size_t)24 << 20));
  unsigned short* wob = (unsigned short*)(ws + ((size_t)26 << 20));
  unsigned short* qh  = (unsigned short*)(ws + ((size_t)28 << 20));
  unsigned short* kh  = (unsigned short*)(ws + ((size_t)32 << 20));
  unsigned short* vt  = (unsigned short*)(ws + ((size_t)48 << 20));
  unsigned short* ah  = (unsigned short*)(ws + ((size_t)64 << 20));
  int* meta           = (int*)(ws + ((size_t)68 << 20));
  int* cntp           = meta + 8192;

  mask_meta<<<4, 256, 0, stream>>>(mask, meta, cntp);
  cast_fused<<<3584, 256, 0, stream>>>(x, ctx, Wq, Wk, Wv, Wo, meta, cntp,
                                       xb, cb, wqb, wkb, wvb, wob);
  gemm_qkv<<<1152, 256, 0, stream>>>(xb, cb, wqb, wkb, wvb,
                                     bq, bk, bv, cntp, qh, kh, vt);
  attn_kernel<<<dim3(64, 8), 256, 0, stream>>>(qh, kh, vt, cntp, ah);
  gemm_o<<<dim3(32, 8), 256, 0, stream>>>(ah, wob, bo, (float*)d_out);
}

// Round 10
// 181.375 us; speedup vs baseline: 1.0408x; 1.0408x over previous
//
#include <hip/hip_runtime.h>
#include <hip/hip_bf16.h>
#include <stdint.h>

// ---------------------------------------------------------------------------
// CrossAttention B=4 N=512 M=2048 C=1024 H=16 D=64, bf16 MFMA fp32 accum.
// R19: R17 structure (best measured 183.9us) + T4 counted-vmcnt pipeline.
// R18's K/V 128x128 split regressed (-4.9us incl. ~2-3us fill-variance) ->
// reverted to the dual-KV 128x64 body. New: the k-loop barriers are now
// raw s_barrier with MANUAL counted waits instead of __syncthreads():
//   stage(k+1)  -> s_waitcnt vmcnt(8)  [stage-k done, k+1's 8 stay in flight]
//   s_barrier   -> compute(k) -> s_waitcnt lgkmcnt(0) -> s_barrier
// __syncthreads() compiles to a full vmcnt(0) drain, which stalled the
// freshly-issued next-tile loads every step; counted vmcnt gives them a
// full step + compute phase to land (m218: counted-vs-drain0 is the lever).
// Race audit: per-wave FIFO vmcnt (m135) + symmetric schedules => at
// barrier-exit all waves' stage-k loads complete; WAR on buf^1 protected by
// the post-compute exec barrier. All memory ops ordered via asm "memory".
// Applied to kv_body64, q_body, gemm_o. Values untouched (absmax canary
// 0.0004882812 must hold exactly; any drift = race, revert).
// Carried from R17: 128x64 dual-KV tiles, 2-phase dbuf, bf16 scatter-cast,
// mask_meta scan, frag-major Q/K/V, fixed-max softmax attn, epi_store64.
// ---------------------------------------------------------------------------

typedef __attribute__((ext_vector_type(4))) float f32x4;
typedef __attribute__((ext_vector_type(8))) __bf16 bf16x8;
typedef __attribute__((ext_vector_type(8))) unsigned short u16x8;

#define DEVI __device__ __forceinline__

// SCALE * log2(e): folded into Wq cast so QK^T scores land in log2 units.
#define QSC (0.125f * 1.44269504088896f)

DEVI f32x4 mfma16(u16x8 a, u16x8 b, f32x4 c) {
  return __builtin_amdgcn_mfma_f32_16x16x32_bf16(
      __builtin_bit_cast(bf16x8, a), __builtin_bit_cast(bf16x8, b), c, 0, 0, 0);
}

// round-to-nearest-even fp32 -> bf16
DEVI unsigned short f2bf(float f) {
  union { float f; unsigned int u; } x; x.f = f;
  unsigned int u = x.u;
  return (unsigned short)((u + 0x7fffu + ((u >> 16) & 1u)) >> 16);
}

DEVI float exp2_fast(float x) {
#if __has_builtin(__builtin_amdgcn_exp2f)
  return __builtin_amdgcn_exp2f(x);
#else
  return exp2f(x);
#endif
}

// async global->LDS, 16 bytes per lane (global_load_lds_dwordx4)
DEVI void llds16(const void* g, void* l) {
  __builtin_amdgcn_global_load_lds(
      (const __attribute__((address_space(1))) void*)g,
      (__attribute__((address_space(3))) void*)l, 16, 0, 0);
}

// ---------------------------------------------------------------------------
// Per-batch mask scan: meta[r] = scatter dst for ctx row r (bit31 = valid),
// cnt[b] = number of valid keys. One block per batch.
__global__ __launch_bounds__(256)
void mask_meta(const int* __restrict__ mask, int* __restrict__ meta,
               int* __restrict__ cnt) {
  const int b = blockIdx.x;
  const int tid = threadIdx.x;
  const int* mb = mask + b * 2048;
  int v[8], s = 0;
#pragma unroll
  for (int j = 0; j < 8; ++j) { v[j] = (mb[tid * 8 + j] != 0) ? 1 : 0; s += v[j]; }
  __shared__ int sc[2][256];
  sc[0][tid] = s;
  __syncthreads();
  int src = 0;
  for (int off = 1; off < 256; off <<= 1) {
    int x = sc[src][tid];
    if (tid >= off) x += sc[src][tid - off];
    sc[src ^ 1][tid] = x;
    src ^= 1;
    __syncthreads();
  }
  const int incl = sc[src][tid];   // inclusive over threads 0..tid
  const int c = sc[src][255];
  int pre = incl - s;              // valid rows among elements < tid*8
#pragma unroll
  for (int j = 0; j < 8; ++j) {
    const int p = tid * 8 + j;
    const unsigned dst = v[j] ? (unsigned)pre : (unsigned)(c + (p - pre));
    meta[b * 2048 + p] = (int)(dst | (v[j] ? 0x80000000u : 0u));
    pre += v[j];
  }
  if (tid == 0) cnt[b] = c;
}

// ---------------------------------------------------------------------------
// Casts all fp32 inputs to bf16. Wq gets QSC folded in. ctx rows are
// SCATTERED into compacted order using the precomputed meta[] ranks.
// Grid 3584: [0,512) x; [512,2560) ctx (4 rows/block); [2560,3584) weights.
__global__ __launch_bounds__(256)
void cast_fused(const float* __restrict__ x, const float* __restrict__ ctx,
                const float* __restrict__ wq, const float* __restrict__ wk,
                const float* __restrict__ wv, const float* __restrict__ wo,
                const int* __restrict__ meta, const int* __restrict__ cnt,
                unsigned short* __restrict__ xb, unsigned short* __restrict__ cb,
                unsigned short* __restrict__ wqb, unsigned short* __restrict__ wkb,
                unsigned short* __restrict__ wvb, unsigned short* __restrict__ wob) {
  int bid = blockIdx.x;
  const int tid = threadIdx.x;
  if (bid >= 512 && bid < 2560) {  // ctx scatter, 4 rows per block
    const int r0 = (bid - 512) * 4;
#pragma unroll
    for (int rr = 0; rr < 4; ++rr) {
      const int r = r0 + rr;
      const int b = r >> 11;
      const unsigned mv = (unsigned)meta[r];
      const int valid = (int)(mv >> 31);
      const int dst = (int)(mv & 0x7fffffffu);
      if (!valid && dst >= ((cnt[b] + 255) & ~255)) continue;  // beyond pad
      unsigned short* dp = cb + ((size_t)(b * 2048 + dst)) * 1024 + tid * 4;
      if (valid) {
        const float4 v = *(const float4*)(ctx + ((size_t)r) * 1024 + tid * 4);
        ushort4 o;
        o.x = f2bf(v.x); o.y = f2bf(v.y); o.z = f2bf(v.z); o.w = f2bf(v.w);
        *(ushort4*)dp = o;
      } else {
        ushort4 z; z.x = z.y = z.z = z.w = 0;
        *(ushort4*)dp = z;
      }
    }
    return;
  }
  const float* src; unsigned short* dst; float scale = 1.f;
  if (bid < 512) { src = x; dst = xb; }
  else {
    bid -= 2560;
    const int w = bid >> 8; bid &= 255;
    src = (w == 0) ? wq : (w == 1) ? wk : (w == 2) ? wv : wo;
    dst = (w == 0) ? wqb : (w == 1) ? wkb : (w == 2) ? wvb : wob;
    if (w == 0) scale = QSC;
  }
  const int e0 = bid * 4096 + tid * 4;
#pragma unroll
  for (int it = 0; it < 4; ++it) {
    const int e = e0 + it * 1024;
    const float4 v = *(const float4*)(src + e);
    ushort4 o;
    o.x = f2bf(v.x * scale); o.y = f2bf(v.y * scale);
    o.z = f2bf(v.z * scale); o.w = f2bf(v.w * scale);
    *(ushort4*)(dst + e) = o;
  }
}

// ---------------------------------------------------------------------------
// Epilogue helper (128x128 tiles, Q projection): stage C through LDS, store
// coalesced. mode 0: fragment-major [bh][grp=idx/16][d8][idx&15][8].
DEVI void epi_store(f32x4 (&acc)[4][4], const float* __restrict__ bias,
                    float bscale, void* __restrict__ Cout,
                    int bm, int bn, int logS,
                    unsigned short* cst, int tid, int wave, int l15, int quad) {
  const int wm = wave & 1, wn = wave >> 1;
  __syncthreads();
  for (int half = 0; half < 2; ++half) {
    if (wm == half) {
#pragma unroll
      for (int mi = 0; mi < 4; ++mi)
#pragma unroll
        for (int ni = 0; ni < 4; ++ni)
#pragma unroll
          for (int r = 0; r < 4; ++r) {
            int lrow = mi * 16 + quad * 4 + r;          // 0..63
            int lcol = wn * 64 + ni * 16 + l15;         // 0..127
            unsigned short bv = f2bf(acc[mi][ni][r] + bias[bn + lcol] * bscale);
            cst[lrow * 136 + lcol] = bv;
          }
    }
    __syncthreads();
    {
      // fragment-major: one u16x8 = (idx fixed, 8 consecutive d)
      int lrow = tid >> 2, cc = (tid & 3) * 32;
      int row = bm + half * 64 + lrow;
      int S = 1 << logS;
      int b = row >> logS, sl = row & (S - 1);
#pragma unroll
      for (int j = 0; j < 4; ++j) {
        int col = bn + cc + j * 8;
        int h = col >> 6, d8 = (col & 63) >> 3;
        size_t base = (((size_t)(b * 16 + h)) << logS) * 64 +
                      (size_t)(sl >> 4) * 1024 + d8 * 128 + (sl & 15) * 8;
        *(u16x8*)&((unsigned short*)Cout)[base] =
            *(const u16x8*)&cst[lrow * 136 + cc + j * 8];
      }
    }
    __syncthreads();
  }
}

// ---------------------------------------------------------------------------
// Epilogue for 128x64 KV tiles. All 4 waves write disjoint (row,col) ranges
// -> single write pass. mode 0: K-heads fragment-major (logS=11).
// mode 2: V^T fragment-major [bh][key/64][d/16][key8][d&15][8].
DEVI void epi_store64(f32x4 (&acc)[4][2], const float* __restrict__ bias,
                      void* __restrict__ Cout, int bm, int bn, int mode,
                      unsigned short* cst, int tid, int wave, int l15, int quad) {
  const int wm = wave & 1, wn = wave >> 1;
  __syncthreads();
#pragma unroll
  for (int mi = 0; mi < 4; ++mi)
#pragma unroll
    for (int ni = 0; ni < 2; ++ni)
#pragma unroll
      for (int r = 0; r < 4; ++r) {
        int lrow = wm * 64 + mi * 16 + quad * 4 + r;  // 0..127 (key)
        int lcol = wn * 32 + ni * 16 + l15;           // 0..63  (d)
        unsigned short bv = f2bf(acc[mi][ni][r] + bias[bn + lcol]);
        if (mode == 0) cst[lrow * 72 + lcol] = bv;
        else           cst[lcol * 136 + lrow] = bv;   // transposed
      }
  __syncthreads();
  if (mode == 0) {
    // one u16x8 = (key fixed, 8 consecutive d); 256 thr x 4 = 1024 octets
    int lrow = tid >> 1, cc = (tid & 1) * 32;
    int row = bm + lrow;
    int b = row >> 11, sl = row & 2047;
#pragma unroll
    for (int j = 0; j < 4; ++j) {
      int col = bn + cc + j * 8;
      int h = col >> 6, d8 = (col & 63) >> 3;
      size_t base = (((size_t)(b * 16 + h)) << 11) * 64 +
                    (size_t)(sl >> 4) * 1024 + d8 * 128 + (sl & 15) * 8;
      *(u16x8*)&((unsigned short*)Cout)[base] =
          *(const u16x8*)&cst[lrow * 72 + cc + j * 8];
    }
  } else {
    // one u16x8 = (d fixed, 8 consecutive keys)
    int c = tid >> 2, rc = (tid & 3) * 32;
    int gc = bn + c, h = gc >> 6, d = gc & 63;
    int b = bm >> 11;
#pragma unroll
    for (int j = 0; j < 4; ++j) {
      int key = (bm & 2047) + rc + j * 8;
      size_t base = (size_t)(b * 16 + h) * 131072 +
                    (size_t)(((key >> 6) * 4 + (d >> 4)) * 8 + ((key >> 3) & 7)) * 128 +
                    (d & 15) * 8;
      *(u16x8*)&((unsigned short*)Cout)[base] =
          *(const u16x8*)&cst[c * 136 + rc + j * 8];
    }
  }
  __syncthreads();
}

// ---------------------------------------------------------------------------
// Fused K+V body, 128 rows x 64 cols per block, double-buffered with COUNTED
// vmcnt (T4): stage(k+1) issues 8 llds16 into buf^1; s_waitcnt vmcnt(8)
// waits only for stage-k's loads (the new 8 stay in flight across compute
// AND the barriers); raw s_barrier pair instead of __syncthreads() so the
// compiler never emits a vmcnt(0) drain in-loop.
// Per-phase buffer: As 16KB + Ks 8KB + Vs 8KB = 32 KB; dbuf 64 KB.
DEVI void kv_body64(const unsigned short* __restrict__ A,
                    const unsigned short* __restrict__ WK,
                    const unsigned short* __restrict__ WV,
                    const float* __restrict__ bk, const float* __restrict__ bv,
                    unsigned short* __restrict__ kh, unsigned short* __restrict__ vt,
                    int bm, int bn, unsigned short* sh) {
  constexpr int K = 1024;
  const int tid = threadIdx.x;
  const int wave = tid >> 6, lane = tid & 63;
  const int l15 = lane & 15, quad = lane >> 4;
  const int wm = wave & 1, wn = wave >> 1;

  auto stage = [&](int p, int k0) {
    unsigned short* As = sh + p * 16384;
    unsigned short* Ks = As + 8192;
    unsigned short* Vs = As + 12288;
#pragma unroll
    for (int c = 0; c < 4; ++c) {
      int s = c * 256 + tid;
      int m = s >> 3, k8 = (s & 7) ^ (m & 7);
      llds16(A + (size_t)(bm + m) * K + k0 + k8 * 8, &As[s * 8]);
    }
#pragma unroll
    for (int c = 0; c < 2; ++c) {
      int s = c * 256 + tid;
      int m = s >> 3, k8 = (s & 7) ^ (m & 7);
      llds16(WK + (size_t)(bn + m) * K + k0 + k8 * 8, &Ks[s * 8]);
      llds16(WV + (size_t)(bn + m) * K + k0 + k8 * 8, &Vs[s * 8]);
    }
  };

  f32x4 ak[4][2] = {}, av[4][2] = {};

  stage(0, 0);

  int cur = 0;
  for (int k0 = 0; k0 < K; k0 += 64) {
    if (k0 + 64 < K) {
      stage(cur ^ 1, k0 + 64);                       // 8 more in flight
      asm volatile("s_waitcnt vmcnt(8)" ::: "memory");  // stage-k complete
    } else {
      asm volatile("s_waitcnt vmcnt(0)" ::: "memory");
    }
    __builtin_amdgcn_s_barrier();                    // all waves' stage-k done
    const unsigned short* As = sh + cur * 16384;
    const unsigned short* Ks = As + 8192;
    const unsigned short* Vs = As + 12288;
#pragma unroll
    for (int ks = 0; ks < 2; ++ks) {
      const int k8 = ks * 4 + quad;
      u16x8 af[4], bf[2];
#pragma unroll
      for (int i = 0; i < 4; ++i) {
        int m = wm * 64 + i * 16 + l15;
        af[i] = *(const u16x8*)(&As[(m * 8 + (k8 ^ (m & 7))) * 8]);
      }
#pragma unroll
      for (int i = 0; i < 2; ++i) {
        int n = wn * 32 + i * 16 + l15;
        bf[i] = *(const u16x8*)(&Ks[(n * 8 + (k8 ^ (n & 7))) * 8]);
      }
#pragma unroll
      for (int mi = 0; mi < 4; ++mi)
#pragma unroll
        for (int ni = 0; ni < 2; ++ni)
          ak[mi][ni] = mfma16(af[mi], bf[ni], ak[mi][ni]);
#pragma unroll
      for (int i = 0; i < 2; ++i) {
        int n = wn * 32 + i * 16 + l15;
        bf[i] = *(const u16x8*)(&Vs[(n * 8 + (k8 ^ (n & 7))) * 8]);
      }
#pragma unroll
      for (int mi = 0; mi < 4; ++mi)
#pragma unroll
        for (int ni = 0; ni < 2; ++ni)
          av[mi][ni] = mfma16(af[mi], bf[ni], av[mi][ni]);
    }
    asm volatile("s_waitcnt lgkmcnt(0)" ::: "memory");  // our ds_reads retired
    __builtin_amdgcn_s_barrier();                    // WAR: buf[cur] reusable
    cur ^= 1;
  }

  epi_store64(ak, bk, kh, bm, bn, 0, sh, tid, wave, l15, quad);
  epi_store64(av, bv, vt, bm, bn, 2, sh, tid, wave, l15, quad);
}

// Single-GEMM body (Q projection), 128x128, counted-vmcnt dbuf, mode 0 epi.
// Per-phase buffer: As 16KB + Bs 16KB = 32 KB.
DEVI void q_body(const unsigned short* __restrict__ A,
                 const unsigned short* __restrict__ W,
                 const float* __restrict__ bias,
                 unsigned short* __restrict__ Cout,
                 int bm, int bn, unsigned short* sh) {
  constexpr int K = 1024;
  const int tid = threadIdx.x;
  const int wave = tid >> 6, lane = tid & 63;
  const int l15 = lane & 15, quad = lane >> 4;
  const int wm = wave & 1, wn = wave >> 1;

  auto stage = [&](int p, int k0) {
    unsigned short* As = sh + p * 16384;
    unsigned short* Bs = As + 8192;
#pragma unroll
    for (int c = 0; c < 4; ++c) {
      int s = c * 256 + tid;
      int m = s >> 3, k8 = (s & 7) ^ (m & 7);
      llds16(A + (size_t)(bm + m) * K + k0 + k8 * 8, &As[s * 8]);
      llds16(W + (size_t)(bn + m) * K + k0 + k8 * 8, &Bs[s * 8]);
    }
  };

  f32x4 acc[4][4] = {};

  stage(0, 0);

  int cur = 0;
  for (int k0 = 0; k0 < K; k0 += 64) {
    if (k0 + 64 < K) {
      stage(cur ^ 1, k0 + 64);
      asm volatile("s_waitcnt vmcnt(8)" ::: "memory");
    } else {
      asm volatile("s_waitcnt vmcnt(0)" ::: "memory");
    }
    __builtin_amdgcn_s_barrier();
    const unsigned short* As = sh + cur * 16384;
    const unsigned short* Bs = As + 8192;
#pragma unroll
    for (int ks = 0; ks < 2; ++ks) {
      const int k8 = ks * 4 + quad;
      u16x8 af[4], bf[4];
#pragma unroll
      for (int i = 0; i < 4; ++i) {
        int m = wm * 64 + i * 16 + l15;
        af[i] = *(const u16x8*)(&As[(m * 8 + (k8 ^ (m & 7))) * 8]);
        int n = wn * 64 + i * 16 + l15;
        bf[i] = *(const u16x8*)(&Bs[(n * 8 + (k8 ^ (n & 7))) * 8]);
      }
#pragma unroll
      for (int mi = 0; mi < 4; ++mi)
#pragma unroll
        for (int ni = 0; ni < 4; ++ni)
          acc[mi][ni] = mfma16(af[mi], bf[ni], acc[mi][ni]);
    }
    asm volatile("s_waitcnt lgkmcnt(0)" ::: "memory");
    __builtin_amdgcn_s_barrier();
    cur ^= 1;
  }

  epi_store(acc, bias, QSC, Cout, bm, bn, 9, sh, tid, wave, l15, quad);
}

// Fused Q/K/V projection, DENSE remap. Flat grid 1152 blocks. KV tiles
// 128x64 (y over 16); ~640 live blocks (~2.5/CU). LDS 64 KB (2 blocks/CU).
// ids [0, L*16)         : live K+V dual tiles
// ids [L*16, L*16+128)  : Q single tiles (128x128)
// ids >= L*16+128       : exit immediately (at the END of dispatch order)
__global__ __launch_bounds__(256, 2)
void gemm_qkv(const unsigned short* __restrict__ xb,
              const unsigned short* __restrict__ cb,
              const unsigned short* __restrict__ wq,
              const unsigned short* __restrict__ wk,
              const unsigned short* __restrict__ wv,
              const float* __restrict__ bq, const float* __restrict__ bk,
              const float* __restrict__ bv,
              const int* __restrict__ cnt,
              unsigned short* __restrict__ qh, unsigned short* __restrict__ kh,
              unsigned short* __restrict__ vt) {
  __shared__ __align__(16) unsigned short sh[32768];  // 64 KB, 2 phases
  const int id = blockIdx.x;

  const int nb0 = ((cnt[0] + 255) & ~255) >> 7;
  const int nb1 = ((cnt[1] + 255) & ~255) >> 7;
  const int nb2 = ((cnt[2] + 255) & ~255) >> 7;
  const int nb3 = ((cnt[3] + 255) & ~255) >> 7;
  const int L = nb0 + nb1 + nb2 + nb3;
  if (id < L * 16) {
    int xl = id >> 4, y = id & 15, b = 0;
    if (xl >= nb0) { xl -= nb0; b = 1;
      if (xl >= nb1) { xl -= nb1; b = 2;
        if (xl >= nb2) { xl -= nb2; b = 3; } } }
    kv_body64(cb, wk, wv, bk, bv, kh, vt, b * 2048 + xl * 128, y * 64, sh);
  } else if (id < L * 16 + 128) {
    const int q = id - L * 16;
    q_body(xb, wq, bq, qh, (q & 15) * 128, (q >> 4) * 128, sh);
  }
}

// ---------------------------------------------------------------------------
// Output projection: out[2048,1024] fp32 = ah @ Wo^T + bo. 64x128 tile,
// grid (32, 8) = 256 blocks, counted-vmcnt dbuf k-loop.
// Per-phase buffer: As 8KB + Bs 16KB = 24 KB; 48 KB total.
// The ONLY kernel that touches d_out.
__global__ __launch_bounds__(256)
void gemm_o(const unsigned short* __restrict__ A,
            const unsigned short* __restrict__ W,
            const float* __restrict__ bo, float* __restrict__ out) {
  constexpr int K = 1024;
  __shared__ __align__(16) unsigned short sh[24576];  // 48 KB, 2 phases

  const int tid = threadIdx.x;
  const int wave = tid >> 6, lane = tid & 63;
  const int l15 = lane & 15, quad = lane >> 4;
  const int bm = blockIdx.x * 64, bn = blockIdx.y * 128;

  auto stage = [&](int p, int k0) {
    unsigned short* As = sh + p * 12288;
    unsigned short* Bs = As + 4096;
#pragma unroll
    for (int c = 0; c < 2; ++c) {
      int s = c * 256 + tid;
      int m = s >> 3, k8 = (s & 7) ^ (m & 7);
      llds16(A + (size_t)(bm + m) * K + k0 + k8 * 8, &As[s * 8]);
    }
#pragma unroll
    for (int c = 0; c < 4; ++c) {
      int s = c * 256 + tid;
      int m = s >> 3, k8 = (s & 7) ^ (m & 7);
      llds16(W + (size_t)(bn + m) * K + k0 + k8 * 8, &Bs[s * 8]);
    }
  };

  f32x4 acc[4][2] = {};

  stage(0, 0);

  int cur = 0;
  for (int k0 = 0; k0 < K; k0 += 64) {
    if (k0 + 64 < K) {
      stage(cur ^ 1, k0 + 64);
      asm volatile("s_waitcnt vmcnt(6)" ::: "memory");  // 6 loads per stage
    } else {
      asm volatile("s_waitcnt vmcnt(0)" ::: "memory");
    }
    __builtin_amdgcn_s_barrier();
    const unsigned short* As = sh + cur * 12288;
    const unsigned short* Bs = As + 4096;
#pragma unroll
    for (int ks = 0; ks < 2; ++ks) {
      const int k8 = ks * 4 + quad;
      u16x8 af[4], bf[2];
#pragma unroll
      for (int i = 0; i < 4; ++i) {
        int m = i * 16 + l15;
        af[i] = *(const u16x8*)(&As[(m * 8 + (k8 ^ (m & 7))) * 8]);
      }
#pragma unroll
      for (int i = 0; i < 2; ++i) {
        int n = wave * 32 + i * 16 + l15;
        bf[i] = *(const u16x8*)(&Bs[(n * 8 + (k8 ^ (n & 7))) * 8]);
      }
#pragma unroll
      for (int mi = 0; mi < 4; ++mi)
#pragma unroll
        for (int ni = 0; ni < 2; ++ni)
          acc[mi][ni] = mfma16(af[mi], bf[ni], acc[mi][ni]);
    }
    asm volatile("s_waitcnt lgkmcnt(0)" ::: "memory");
    __builtin_amdgcn_s_barrier();
    cur ^= 1;
  }

#pragma unroll
  for (int mi = 0; mi < 4; ++mi)
#pragma unroll
    for (int ni = 0; ni < 2; ++ni)
#pragma unroll
      for (int r = 0; r < 4; ++r) {
        int row = bm + mi * 16 + quad * 4 + r;
        int col = bn + wave * 32 + ni * 16 + l15;
        out[(size_t)row * 1024 + col] = acc[mi][ni][r] + bo[col];
      }
}

// ---------------------------------------------------------------------------
// Split-K flash attention over COMPACTED keys, fixed-max softmax.
// Grid (64 bh, 8 qblk), block 256. cnt from the precomputed scan (1 uniform
// load). Wave w covers keys {w*64 + 256t}, t < T = ceil(cnt/256). Bias
// register-computed: uniform -8 for full tiles, per-element (-8 / -1e30)
// when the stripe straddles cnt (pad K/V rows come from zero-filled ctx
// rows -> finite). No barriers in the main loop. Q/K/V FRAGMENT-MAJOR
// (contiguous 1KB wave-loads).
// launch_bounds(256,2): VGPR cap 256 (audit ~210) -> 2 blocks/CU resident.
// PS: p_lds row stride in u16. MUST be == 0 mod 8 (16 B) -- P fragments are
// read as u16x8 (ds_read_b128); any other stride misaligns odd q-rows.
#define PS 72
__global__ __launch_bounds__(256, 2)
void attn_kernel(const unsigned short* __restrict__ Q,   // frag-major [64][32][8][16][8]
                 const unsigned short* __restrict__ K,   // frag-major [64][128][8][16][8]
                 const unsigned short* __restrict__ Vt,  // frag-major [64][32][4][8][16][8]
                 const int* __restrict__ cnt,            // [4]
                 unsigned short* __restrict__ O) {       // [4][512][1024]
  __shared__ __align__(16) unsigned short p_lds[4][2][16 * PS];
  __shared__ float l_lds[4][64];
  __shared__ __align__(16) float o_comb[64][68];

  const int tid = threadIdx.x;
  const int wave = tid >> 6, lane = tid & 63;
  const int l15 = lane & 15, quad = lane >> 4;
  const int bh = blockIdx.x, b = bh >> 4, h = bh & 15;
  const int q0 = blockIdx.y * 64;

  const int c = cnt[b];
  const int T = (c + 255) >> 8;  // number of 256-key macro tiles

  const unsigned short* Qb = Q + (size_t)bh * 32768 + (size_t)(q0 >> 4) * 1024;
  const unsigned short* Kb = K + (size_t)bh * 131072;
  const unsigned short* Vb = Vt + (size_t)bh * 131072;

  // Q fragments (frag-major): one contiguous 1KB wave-load each.
  u16x8 aq[4][2];
#pragma unroll
  for (int qg = 0; qg < 4; ++qg)
#pragma unroll
    for (int ks = 0; ks < 2; ++ks)
      aq[qg][ks] = *(const u16x8*)(Qb + ((qg * 8 + ks * 4 + quad) * 16 + l15) * 8);

  f32x4 o_acc[4][4] = {};
  float l_s[4] = {0.f, 0.f, 0.f, 0.f};

  u16x8 kf[2][4];

  auto load_k = [&](int kb) {
    const int kg0 = kb >> 4;
#pragma unroll
    for (int ns = 0; ns < 4; ++ns)
#pragma unroll
      for (int ks = 0; ks < 2; ++ks)
        kf[ks][ns] = *(const u16x8*)(Kb + (((size_t)(kg0 + ns) * 8 + ks * 4 + quad) * 16 + l15) * 8);
  };

  load_k(wave * 64);

#pragma unroll 1
  for (int t = 0; t < T; ++t) {
    const int kb = wave * 64 + t * 256;
    const int kb_next = kb + (t + 1 < T ? 256 : 0);

    // V^T frags (frag-major, contiguous): consumed in PV, well after issue.
    u16x8 vf[2][4];
    const int kt4 = (kb >> 6) * 4;
#pragma unroll
    for (int nd = 0; nd < 4; ++nd)
#pragma unroll
      for (int ks = 0; ks < 2; ++ks)
        vf[ks][nd] = *(const u16x8*)(Vb + (((size_t)(kt4 + nd) * 8 + ks * 4 + quad) * 16 + l15) * 8);

    // register bias: uniform -8 unless this 64-key stripe straddles cnt
    f32x4 bfr[4];
    if (kb + 64 <= c) {
#pragma unroll
      for (int ns = 0; ns < 4; ++ns)
        bfr[ns] = f32x4{-8.f, -8.f, -8.f, -8.f};
    } else {
#pragma unroll
      for (int ns = 0; ns < 4; ++ns)
#pragma unroll
        for (int r = 0; r < 4; ++r)
          bfr[ns][r] = (kb + ns * 16 + quad * 4 + r < c) ? -8.f : -1e30f;
    }

#pragma unroll
    for (int qg = 0; qg < 4; ++qg) {
      // S^T tile: D[key = ns*16+quad*4+r][q = l15], C-init = bias (-8 shift)
      f32x4 sfr[4];
#pragma unroll
      for (int ns = 0; ns < 4; ++ns) {
        f32x4 sa = bfr[ns];
#pragma unroll
        for (int ks = 0; ks < 2; ++ks)
          sa = mfma16(kf[ks][ns], aq[qg][ks], sa);
        sfr[ns] = sa;
      }

      // kf dead after qg==3's S: reload for next tile now (covered by the
      // remaining softmax + PV of this qg).
      if (qg == 3) load_k(kb_next);

      float rsum = 0.f;
#pragma unroll
      for (int ns = 0; ns < 4; ++ns) {
        unsigned int pr[4];
#pragma unroll
        for (int r = 0; r < 4; ++r) {
          float p = exp2_fast(sfr[ns][r]);
          unsigned int u = __builtin_bit_cast(unsigned int, p) & 0xffff0000u;
          rsum += __builtin_bit_cast(float, u);  // sum TRUNCATED p: consistent with PV
          pr[r] = u;
        }
        uint2 pw;
        pw.x = __builtin_amdgcn_perm(pr[1], pr[0], 0x07060302u);
        pw.y = __builtin_amdgcn_perm(pr[3], pr[2], 0x07060302u);
        *(uint2*)&p_lds[wave][qg & 1][l15 * PS + ns * 16 + quad * 4] = pw;
      }
      rsum += __shfl_xor(rsum, 16, 64);
      rsum += __shfl_xor(rsum, 32, 64);
      l_s[qg] += rsum;

      // PV: A = P (lane=q, elems=key) from p_lds; B = V^T frags
#pragma unroll
      for (int ks = 0; ks < 2; ++ks) {
        u16x8 pf = *(const u16x8*)&p_lds[wave][qg & 1][l15 * PS + ks * 32 + quad * 8];
#pragma unroll
        for (int nd = 0; nd < 4; ++nd)
          o_acc[qg][nd] = mfma16(pf, vf[ks][nd], o_acc[qg][nd]);
      }
    }
  }

  // ---- combine the 4 waves' partial (l, o): plain sums (fixed max) ----
  if (quad == 0) {
#pragma unroll
    for (int qg = 0; qg < 4; ++qg)
      l_lds[wave][qg * 16 + l15] = l_s[qg];
  }
  __syncthreads();

  for (int w = 0; w < 4; ++w) {
    if (wave == w) {
#pragma unroll
      for (int qg = 0; qg < 4; ++qg)
#pragma unroll
        for (int r = 0; r < 4; ++r) {
          const int q = qg * 16 + quad * 4 + r;
#pragma unroll
          for (int nd = 0; nd < 4; ++nd) {
            const int d = nd * 16 + l15;
            float v = o_acc[qg][nd][r];
            if (w == 0) o_comb[q][d] = v;
            else        o_comb[q][d] += v;
          }
        }
    }
    __syncthreads();
  }

  // ---- final normalize + store (two u16x8 per thread) ----
  {
    const int q = tid >> 2, dc = (tid & 3) * 16;
    const float inv = 1.f / (l_lds[0][q] + l_lds[1][q] + l_lds[2][q] + l_lds[3][q]);
    unsigned short* Ob = O + ((size_t)(b * 512 + q0 + q)) * 1024 + h * 64 + dc;
    u16x8 o1, o2;
#pragma unroll
    for (int j = 0; j < 8; ++j) o1[j] = f2bf(o_comb[q][dc + j] * inv);
#pragma unroll
    for (int j = 0; j < 8; ++j) o2[j] = f2bf(o_comb[q][dc + 8 + j] * inv);
    *(u16x8*)(Ob) = o1;
    *(u16x8*)(Ob + 8) = o2;
  }
}

// ---------------------------------------------------------------------------
extern "C" void kernel_launch(void* const* d_in, const int* in_sizes, int n_in,
                              void* d_out, int out_size, void* d_ws, size_t ws_size,
                              hipStream_t stream) {
  const float* x   = (const float*)d_in[0];
  const float* ctx = (const float*)d_in[1];
  const int* mask  = (const int*)d_in[2];
  const float* Wq  = (const float*)d_in[3];
  const float* bq  = (const float*)d_in[4];
  const float* Wk  = (const float*)d_in[5];
  const float* bk  = (const float*)d_in[6];
  const float* Wv  = (const float*)d_in[7];
  const float* bv  = (const float*)d_in[8];
  const float* Wo  = (const float*)d_in[9];
  const float* bo  = (const float*)d_in[10];

  char* ws = (char*)d_ws;
  // [MB] xb 0-4, cb 4-20, w 20-28, qh 28-32, kh 32-48, vt 48-64, ah 64-68,
  // meta/cnt at 68 (8192+4 ints). All ws contents are produced fresh every
  // launch; d_out is written ONLY by gemm_o.
  unsigned short* xb  = (unsigned short*)(ws + ((size_t)0  << 20));
  unsigned short* cb  = (unsigned short*)(ws + ((size_t)4  << 20));
  unsigned short* wqb = (unsigned short*)(ws + ((size_t)20 << 20));
  unsigned short* wkb = (unsigned short*)(ws + ((size_t)22 << 20));
  unsigned short* wvb = (unsigned short*)(ws + ((size_t)24 << 20));
  unsigned short* wob = (unsigned short*)(ws + ((size_t)26 << 20));
  unsigned short* qh  = (unsigned short*)(ws + ((size_t)28 << 20));
  unsigned short* kh  = (unsigned short*)(ws + ((size_t)32 << 20));
  unsigned short* vt  = (unsigned short*)(ws + ((size_t)48 << 20));
  unsigned short* ah  = (unsigned short*)(ws + ((size_t)64 << 20));
  int* meta           = (int*)(ws + ((size_t)68 << 20));
  int* cntp           = meta + 8192;

  mask_meta<<<4, 256, 0, stream>>>(mask, meta, cntp);
  cast_fused<<<3584, 256, 0, stream>>>(x, ctx, Wq, Wk, Wv, Wo, meta, cntp,
                                       xb, cb, wqb, wkb, wvb, wob);
  gemm_qkv<<<1152, 256, 0, stream>>>(xb, cb, wqb, wkb, wvb,
                                     bq, bk, bv, cntp, qh, kh, vt);
  attn_kernel<<<dim3(64, 8), 256, 0, stream>>>(qh, kh, vt, cntp, ah);
  gemm_o<<<dim3(32, 8), 256, 0, stream>>>(ah, wob, bo, (float*)d_out);
}